// Round 10
// baseline (195.832 us; speedup 1.0000x reference)
//
#include <hip/hip_runtime.h>

#define DIM 1024
#define NHEADS 16
#define DH 64
#define BATCH 2
#define SEQ 2048

typedef float f32x4 __attribute__((ext_vector_type(4)));
typedef short s16x8 __attribute__((ext_vector_type(8)));
typedef short s16x4 __attribute__((ext_vector_type(4)));

__device__ __forceinline__ short f2bf(float f) {
    union { float f; unsigned u; } v; v.f = f;
    unsigned r = v.u + 0x7fffu + ((v.u >> 16) & 1u);   // RNE to bf16
    return (short)(r >> 16);
}

// packed f32x2 -> bf16x2 (low = a, high = b); HW instr on gfx950 if available
#if defined(__has_builtin)
#if __has_builtin(__builtin_amdgcn_cvt_pk_bf16_f32)
#define HAVE_PK_BF16 1
#endif
#endif
__device__ __forceinline__ unsigned f2bf_pk(float a, float b) {
#ifdef HAVE_PK_BF16
    typedef __bf16 bf16x2_t __attribute__((ext_vector_type(2)));
    bf16x2_t r = __builtin_amdgcn_cvt_pk_bf16_f32(a, b);
    return __builtin_bit_cast(unsigned, r);
#else
    return ((unsigned)(unsigned short)f2bf(b) << 16) | (unsigned short)f2bf(a);
#endif
}
__device__ __forceinline__ s16x4 pk4(float a, float b, float c, float d) {
    union { unsigned u[2]; s16x4 v; } x;
    x.u[0] = f2bf_pk(a, b); x.u[1] = f2bf_pk(c, d);
    return x.v;
}

// native exp2
#if defined(__has_builtin)
#if __has_builtin(__builtin_amdgcn_exp2f)
#define EXP2(x) __builtin_amdgcn_exp2f(x)
#endif
#endif
#ifndef EXP2
#define EXP2(x) exp2f(x)
#endif

// async global->LDS, 16 B per lane (GEMM staging)
__device__ __forceinline__ void gld16(const void* g, void* l) {
    __builtin_amdgcn_global_load_lds(
        (const __attribute__((address_space(1))) void*)g,
        (__attribute__((address_space(3))) void*)l, 16, 0, 0);
}

// ---------------- merged prep: q fp32->bf16 convert + weight transpose ----------------
// blocks [0,2048): convert 2048 floats each; blocks [2048,4096): transpose Wq|Wkv|Wo -> WT
__global__ __launch_bounds__(256) void prep_kernel(
    const float* __restrict__ X, short* __restrict__ Y,
    const float* __restrict__ Wq, const float* __restrict__ Wkv,
    const float* __restrict__ Wo, short* __restrict__ WT)
{
    const int t = threadIdx.x;
    if (blockIdx.x < 2048) {
        const int i = (blockIdx.x * 256 + t) * 8;
        float4 a = *(const float4*)(X + i);
        float4 b = *(const float4*)(X + i + 4);
        union { unsigned u[4]; s16x8 v; } o;
        o.u[0] = f2bf_pk(a.x, a.y); o.u[1] = f2bf_pk(a.z, a.w);
        o.u[2] = f2bf_pk(b.x, b.y); o.u[3] = f2bf_pk(b.z, b.w);
        *(s16x8*)(Y + i) = o.v;
    } else {
        const int i2 = blockIdx.x - 2048;
        const int bx = i2 & 63, by = i2 >> 6;
        const int ng = bx * 64 + (t & 63);           // 0..4095
        const int k0 = (by * 4 + (t >> 6)) * 8;
        const float* W; int n, N;
        if (ng < 1024)      { W = Wq;  n = ng;        N = 1024; }
        else if (ng < 3072) { W = Wkv; n = ng - 1024; N = 2048; }
        else                { W = Wo;  n = ng - 3072; N = 1024; }
        float v[8];
#pragma unroll
        for (int j = 0; j < 8; ++j) v[j] = W[(size_t)(k0 + j) * N + n];
        union { unsigned u[4]; s16x8 s; } o;
        o.u[0] = f2bf_pk(v[0], v[1]); o.u[1] = f2bf_pk(v[2], v[3]);
        o.u[2] = f2bf_pk(v[4], v[5]); o.u[3] = f2bf_pk(v[6], v[7]);
        *(s16x8*)&WT[(size_t)ng * 1024 + k0] = o.s;
    }
}

// ---------------- V part of QKV -> VtG[(b*NH+h)*64+dv][SEQ] ----------------
__global__ __launch_bounds__(256) void transpose_v_kernel(
    const short* __restrict__ QKV, short* __restrict__ VtG)
{
    const int t = threadIdx.x;
    const int tok0 = blockIdx.x * 64;
    const int h = blockIdx.y, b = blockIdx.z;
    __shared__ short L[64 * 72];
    const short* src = QKV + (size_t)(b * SEQ + tok0) * 3072 + 2048 + h * 64;
#pragma unroll
    for (int p = 0; p < 2; ++p) {
        int r = p * 32 + (t >> 3);
        *(s16x8*)&L[r * 72 + (t & 7) * 8] = *(const s16x8*)(src + (size_t)r * 3072 + (t & 7) * 8);
    }
    __syncthreads();
    short* dst = VtG + (size_t)(b * NHEADS + h) * 64 * SEQ + tok0;
#pragma unroll
    for (int p = 0; p < 2; ++p) {
        int u = p * 256 + t;
        int dv = u >> 3, c = (u & 7) * 8;
        s16x8 o;
#pragma unroll
        for (int j = 0; j < 8; ++j) o[j] = L[(c + j) * 72 + dv];
        *(s16x8*)(dst + (size_t)dv * SEQ + c) = o;
    }
}

// ---------------- bf16 MFMA GEMM: C = A @ Bt^T, epilogue (acc+bias)*scale ----------------
// r10: BK 32->64 (halves barrier count: 16 iters, 32 MFMA/iter/wave) + both-sides XOR
// swizzle (rule #21): gld16 writes LDS linearly, so the global SOURCE column-chunk is
// pre-swizzled cc = (lane&7)^(lane>>3) and fragment reads use chunk (ks*4+quad)^(row&7).
// Without swizzle the 128B row stride would be a 16-way bank conflict; with it, 2-way (free).
template<int TM, bool OUT_BF16>
__global__ __launch_bounds__(256) void gemm_mfma_kernel(
    const short* __restrict__ A, const short* __restrict__ Bt,
    const float* __restrict__ bias0, const float* __restrict__ bias1, int nsplit,
    float s0, float s1, void* __restrict__ C, int M, int N)
{
    const int K = 1024;
    constexpr int NI  = (TM == 128) ? 4 : 2;
    constexpr int BK  = 64;
    constexpr int RPW = TM / 4;            // A rows staged per wave
    __shared__ short As[TM * BK];
    __shared__ short Bs[128 * BK];

    const int t    = threadIdx.x;
    const int wave = t >> 6;
    const int lane = t & 63;
    const int col  = lane & 15;
    const int quad = lane >> 4;
    const int m0 = blockIdx.y * TM;
    const int n0 = blockIdx.x * 128;
    const int wroff = (TM == 128) ? (wave >> 1) * 64 : 0;
    const int wcoff = (TM == 128) ? (wave & 1) * 64 : wave * 32;

    f32x4 acc[4][NI];
#pragma unroll
    for (int mi = 0; mi < 4; ++mi)
#pragma unroll
        for (int ni = 0; ni < NI; ++ni) acc[mi][ni] = (f32x4){0.f, 0.f, 0.f, 0.f};

    // stagers: 8 rows per gld16 (lane>>3 = row in group, lane&7 = dest chunk);
    // source chunk XOR-swizzled by row&7 so swizzled READS come from linear WRITES.
    const int sgrow = lane >> 3;                 // 0..7 == (global row)&7
    const int sgc   = (lane & 7) ^ sgrow;        // pre-swizzled source column-chunk
    const short* Ag = A  + (size_t)(m0 + wave * RPW + sgrow) * K + sgc * 8;
    const short* Bg = Bt + (size_t)(n0 + wave * 32  + sgrow) * K + sgc * 8;
    short* AsW = &As[wave * RPW * BK];
    short* BsW = &Bs[wave * 32 * BK];

    for (int k0 = 0; k0 < K; k0 += BK) {
        __syncthreads();
#pragma unroll
        for (int c = 0; c < RPW / 8; ++c)
            gld16(Ag + k0 + (size_t)c * 8 * K, AsW + c * 512);
#pragma unroll
        for (int c = 0; c < 4; ++c)
            gld16(Bg + k0 + (size_t)c * 8 * K, BsW + c * 512);
        __syncthreads();

#pragma unroll
        for (int ks = 0; ks < 2; ++ks) {
            s16x8 aA[4], bB[NI];
#pragma unroll
            for (int mi = 0; mi < 4; ++mi) {
                const int r = wroff + 16 * mi + col;
                aA[mi] = *(const s16x8*)&As[r * BK + (((ks * 4 + quad) ^ (r & 7)) * 8)];
            }
#pragma unroll
            for (int ni = 0; ni < NI; ++ni) {
                const int r = wcoff + 16 * ni + col;
                bB[ni] = *(const s16x8*)&Bs[r * BK + (((ks * 4 + quad) ^ (r & 7)) * 8)];
            }
#pragma unroll
            for (int mi = 0; mi < 4; ++mi)
#pragma unroll
                for (int ni = 0; ni < NI; ++ni)
                    acc[mi][ni] = __builtin_amdgcn_mfma_f32_16x16x32_bf16(aA[mi], bB[ni], acc[mi][ni], 0, 0, 0);
        }
    }

    float bias_v[NI], scale_v[NI];
#pragma unroll
    for (int ni = 0; ni < NI; ++ni) {
        int nb = n0 + wcoff + 16 * ni + col;
        bias_v[ni]  = (nb < nsplit) ? bias0[nb] : bias1[nb - nsplit];
        scale_v[ni] = (nb < nsplit) ? s0 : s1;
    }

#pragma unroll
    for (int mi = 0; mi < 4; ++mi)
#pragma unroll
        for (int ni = 0; ni < NI; ++ni)
#pragma unroll
            for (int r = 0; r < 4; ++r) {
                const int gm = m0 + wroff + 16 * mi + quad * 4 + r;
                const int gn = n0 + wcoff + 16 * ni + col;
                float v = (acc[mi][ni][r] + bias_v[ni]) * scale_v[ni];
                if (OUT_BF16) ((short*)C)[(size_t)gm * N + gn] = f2bf(v);
                else          ((float*)C)[(size_t)gm * N + gn] = v;
            }
}

// ---------------- MFMA flash attention v15 (UNCHANGED from r9: 56.1us measured) ----------
// v7 structure: 128-q tile, 8 waves = 4 q-quarters x 2 key-halves, double-buffered K/Vt,
// ONE barrier/iter, P via per-wave LDS (x32 PV full-rate). + XCD remap (FETCH 69.7->12.3MB).
__global__ __launch_bounds__(512, 4) void attn_v15_kernel(
    const short* __restrict__ QKV,  // [B*S, 3072] bf16 (Q scaled)
    const short* __restrict__ VtG,  // [(b*NH+h)*64+dv][SEQ] bf16
    short* __restrict__ O)          // [B*S, 1024] bf16
{
    const int L = blockIdx.x + 16 * blockIdx.y + 256 * blockIdx.z;  // 0..511
    const int xcd = L & 7, idx = L >> 3;
    const int pair = xcd * 4 + (idx >> 4);     // (b,h) pair, grouped per XCD (2MB L2 set)
    const int qt = idx & 15;
    const int h  = pair & 15;
    const int b  = pair >> 4;
    const int t  = threadIdx.x;
    const int wave = t >> 6;
    const int lane = t & 63;
    const int col  = lane & 15;
    const int quad = lane >> 4;
    const int wq = wave & 3;        // q-quarter (32 rows)
    const int kh = wave >> 2;       // key half (32 of 64)

    // arena 57,344 B: Ks 2x[64*72] | Vt 2x[64*72] | Ps 8x[32*40]
    __shared__ __align__(16) short Lds[28672];
    short* KsB = Lds;                          // + cur*4608
    short* VtB = Lds + 2 * 64 * 72;            // + cur*4608
    short* PsW = Lds + 4 * 64 * 72 + wave * (32 * 40);

    const short* Qg = QKV + (size_t)(b * SEQ + qt * 128) * 3072 + h * DH;
    const short* Kg = QKV + (size_t)(b * SEQ) * 3072 + 1024 + h * DH;
    const short* VtRow = VtG + (size_t)(b * NHEADS + h) * 64 * SEQ;

    // Q B-frags straight from global
    s16x8 aQ[2][2];
#pragma unroll
    for (int tq = 0; tq < 2; ++tq)
#pragma unroll
        for (int kq = 0; kq < 2; ++kq)
            aQ[tq][kq] = *(const s16x8*)(Qg + (size_t)(wq * 32 + 16 * tq + col) * 3072 + kq * 32 + quad * 8);

    f32x4 oa[4][2];                 // [td][tq] : O^T[dv][q] partial (this key half)
    float lsum[2] = {0.f, 0.f};
#pragma unroll
    for (int td = 0; td < 4; ++td)
#pragma unroll
        for (int tq = 0; tq < 2; ++tq) oa[td][tq] = (f32x4){0.f, 0.f, 0.f, 0.f};

    // stagers: 512 threads; srow = token-row (K) / dv-row (Vt), chunk of 16 B
    const int srow = t >> 3;         // 0..63
    const int sc8  = (t & 7) * 8;
    const short* KgS  = Kg + (size_t)srow * 3072 + sc8;
    const short* VtgS = VtRow + (size_t)srow * SEQ + sc8;
    s16x8 kx = *(const s16x8*)KgS;
    s16x8 vx = *(const s16x8*)VtgS;

    for (int kt = 0; kt < SEQ / 64; ++kt) {
        const int cur = kt & 1;
        *(s16x8*)&KsB[cur * 4608 + srow * 72 + sc8] = kx;
        *(s16x8*)&VtB[cur * 4608 + srow * 72 + sc8] = vx;
        {   // prefetch next tile into regs (clamped)
            int nt = (kt + 1 < SEQ / 64) ? kt + 1 : kt;
            kx = *(const s16x8*)(KgS + (size_t)nt * 64 * 3072);
            vx = *(const s16x8*)(VtgS + (size_t)nt * 64);
        }
        __syncthreads();   // double-buffered: single barrier per iter

        // S^T[key(32 of this half)][q(32)] = K . Q^T   (pre-scaled)
        s16x8 aK[2][2];
#pragma unroll
        for (int tk = 0; tk < 2; ++tk)
#pragma unroll
            for (int kq = 0; kq < 2; ++kq)
                aK[tk][kq] = *(const s16x8*)&KsB[cur * 4608 + (kh * 32 + 16 * tk + col) * 72 + kq * 32 + quad * 8];
        f32x4 st[2][2];
        __builtin_amdgcn_s_setprio(1);
#pragma unroll
        for (int tk = 0; tk < 2; ++tk)
#pragma unroll
            for (int tq = 0; tq < 2; ++tq) {
                f32x4 a = (f32x4){0.f, 0.f, 0.f, 0.f};
                a = __builtin_amdgcn_mfma_f32_16x16x32_bf16(aK[tk][0], aQ[tq][0], a, 0, 0, 0);
                a = __builtin_amdgcn_mfma_f32_16x16x32_bf16(aK[tk][1], aQ[tq][1], a, 0, 0, 0);
                st[tk][tq] = a;
            }
        __builtin_amdgcn_s_setprio(0);

        // P = exp2(S^T); b64 writes into P[q][key_local]
#pragma unroll
        for (int tk = 0; tk < 2; ++tk)
#pragma unroll
            for (int tq = 0; tq < 2; ++tq) {
                float p0 = EXP2(st[tk][tq][0]);
                float p1 = EXP2(st[tk][tq][1]);
                float p2 = EXP2(st[tk][tq][2]);
                float p3 = EXP2(st[tk][tq][3]);
                lsum[tq] += (p0 + p1) + (p2 + p3);
                *(s16x4*)&PsW[(16 * tq + col) * 40 + 16 * tk + quad * 4] = pk4(p0, p1, p2, p3);
            }
        asm volatile("s_waitcnt lgkmcnt(0)" ::: "memory");   // P wave-private

        // O^T += V^T . P
        s16x8 bP[2];
#pragma unroll
        for (int tq = 0; tq < 2; ++tq)
            bP[tq] = *(const s16x8*)&PsW[(16 * tq + col) * 40 + quad * 8];
        __builtin_amdgcn_s_setprio(1);
#pragma unroll
        for (int td = 0; td < 4; ++td) {
            const int dv = 16 * td + col;
            s16x8 aV = *(const s16x8*)&VtB[cur * 4608 + dv * 72 + kh * 32 + quad * 8];
#pragma unroll
            for (int tq = 0; tq < 2; ++tq)
                oa[td][tq] = __builtin_amdgcn_mfma_f32_16x16x32_bf16(aV, bP[tq], oa[td][tq], 0, 0, 0);
        }
        __builtin_amdgcn_s_setprio(0);
    }

    // reduce lsum over quad halves (keys spread across quads)
#pragma unroll
    for (int tq = 0; tq < 2; ++tq) {
        lsum[tq] += __shfl_xor(lsum[tq], 16);
        lsum[tq] += __shfl_xor(lsum[tq], 32);
    }

    // cross-wave (key-half) fp32 merge via LDS: single round, 4 slots
    __syncthreads();
    float* red  = (float*)Lds;
    float* redl = red + 4 * 64 * 36;
    if (wave >= 4) {
        const int slot = wave & 3;
#pragma unroll
        for (int td = 0; td < 4; ++td)
#pragma unroll
            for (int tq = 0; tq < 2; ++tq)
#pragma unroll
                for (int r = 0; r < 4; ++r)
                    red[slot * 2304 + (16 * td + quad * 4 + r) * 36 + 16 * tq + col] = oa[td][tq][r];
        if (quad == 0)
#pragma unroll
            for (int tq = 0; tq < 2; ++tq)
                redl[slot * 32 + 16 * tq + col] = lsum[tq];
    }
    __syncthreads();

    // merge + normalize + write (waves 0..3 only)
    if (wave < 4) {
        const int slot = wq;
#pragma unroll
        for (int td = 0; td < 4; ++td)
#pragma unroll
            for (int tq = 0; tq < 2; ++tq)
#pragma unroll
                for (int r = 0; r < 4; ++r)
                    oa[td][tq][r] += red[slot * 2304 + (16 * td + quad * 4 + r) * 36 + 16 * tq + col];
        float inv[2];
#pragma unroll
        for (int tq = 0; tq < 2; ++tq) {
            lsum[tq] += redl[slot * 32 + 16 * tq + col];
            inv[tq] = 1.f / lsum[tq];
        }
        short* Og = O + (size_t)(b * SEQ + qt * 128 + wq * 32) * DIM + h * DH;
#pragma unroll
        for (int td = 0; td < 4; ++td)
#pragma unroll
            for (int tq = 0; tq < 2; ++tq)
                *(s16x4*)(Og + (size_t)(16 * tq + col) * DIM + 16 * td + quad * 4) =
                    pk4(oa[td][tq][0] * inv[tq], oa[td][tq][1] * inv[tq],
                        oa[td][tq][2] * inv[tq], oa[td][tq][3] * inv[tq]);
    }
}

extern "C" void kernel_launch(void* const* d_in, const int* in_sizes, int n_in,
                              void* d_out, int out_size, void* d_ws, size_t ws_size,
                              hipStream_t stream)
{
    const float* q   = (const float*)d_in[0];
    const float* Wq  = (const float*)d_in[1];
    const float* bq  = (const float*)d_in[2];
    const float* Wkv = (const float*)d_in[3];
    const float* bkv = (const float*)d_in[4];
    const float* Wo  = (const float*)d_in[5];
    const float* bo  = (const float*)d_in[6];
    float* out = (float*)d_out;

    const int M = BATCH * SEQ;   // 4096

    // ws (48 MB): qb 8 | WT_all 8 | QKV 24 | AO 8.  VtG (8 MB) lives in d_out (dead before out-GEMM).
    short* qb     = (short*)d_ws;
    short* WT     = qb     + (size_t)M * DIM;             // [4096][1024]: Wq|Wkv|Wo transposed
    short* QKVbuf = WT     + (size_t)4096 * DIM;
    short* AObuf  = QKVbuf + (size_t)M * 3 * DIM;
    short* VtG    = (short*)d_out;

    const float QSCALE = 0.18033688011112042f;   // 0.125 * log2(e)

    prep_kernel<<<4096, 256, 0, stream>>>(q, qb, Wq, Wkv, Wo, WT);

    gemm_mfma_kernel<128, true><<<dim3(3 * DIM / 128, M / 128), 256, 0, stream>>>(
        qb, WT, bq, bkv, DIM, QSCALE, 1.0f, QKVbuf, M, 3 * DIM);
    transpose_v_kernel<<<dim3(SEQ / 64, NHEADS, BATCH), 256, 0, stream>>>(QKVbuf, VtG);
    attn_v15_kernel<<<dim3(SEQ / 128, NHEADS, BATCH), 512, 0, stream>>>(QKVbuf, VtG, AObuf);
    gemm_mfma_kernel<64, false><<<dim3(DIM / 128, M / 64), 256, 0, stream>>>(
        AObuf, WT + (size_t)3072 * 1024, bo, bo, 1 << 30, 1.0f, 1.0f, out, M, DIM);
}

// Round 11
// 189.707 us; speedup vs baseline: 1.0323x; 1.0323x over previous
//
#include <hip/hip_runtime.h>

#define DIM 1024
#define NHEADS 16
#define DH 64
#define BATCH 2
#define SEQ 2048

typedef float f32x4 __attribute__((ext_vector_type(4)));
typedef short s16x8 __attribute__((ext_vector_type(8)));
typedef short s16x4 __attribute__((ext_vector_type(4)));

__device__ __forceinline__ short f2bf(float f) {
    union { float f; unsigned u; } v; v.f = f;
    unsigned r = v.u + 0x7fffu + ((v.u >> 16) & 1u);   // RNE to bf16
    return (short)(r >> 16);
}

// packed f32x2 -> bf16x2 (low = a, high = b); HW instr on gfx950 if available
#if defined(__has_builtin)
#if __has_builtin(__builtin_amdgcn_cvt_pk_bf16_f32)
#define HAVE_PK_BF16 1
#endif
#endif
__device__ __forceinline__ unsigned f2bf_pk(float a, float b) {
#ifdef HAVE_PK_BF16
    typedef __bf16 bf16x2_t __attribute__((ext_vector_type(2)));
    bf16x2_t r = __builtin_amdgcn_cvt_pk_bf16_f32(a, b);
    return __builtin_bit_cast(unsigned, r);
#else
    return ((unsigned)(unsigned short)f2bf(b) << 16) | (unsigned short)f2bf(a);
#endif
}
__device__ __forceinline__ s16x4 pk4(float a, float b, float c, float d) {
    union { unsigned u[2]; s16x4 v; } x;
    x.u[0] = f2bf_pk(a, b); x.u[1] = f2bf_pk(c, d);
    return x.v;
}

// native exp2
#if defined(__has_builtin)
#if __has_builtin(__builtin_amdgcn_exp2f)
#define EXP2(x) __builtin_amdgcn_exp2f(x)
#endif
#endif
#ifndef EXP2
#define EXP2(x) exp2f(x)
#endif

// async global->LDS, 16 B per lane (GEMM staging)
__device__ __forceinline__ void gld16(const void* g, void* l) {
    __builtin_amdgcn_global_load_lds(
        (const __attribute__((address_space(1))) void*)g,
        (__attribute__((address_space(3))) void*)l, 16, 0, 0);
}

// ---------------- merged prep: q fp32->bf16 convert + weight transpose ----------------
// blocks [0,2048): convert 2048 floats each; blocks [2048,4096): transpose Wq|Wkv|Wo -> WT
__global__ __launch_bounds__(256) void prep_kernel(
    const float* __restrict__ X, short* __restrict__ Y,
    const float* __restrict__ Wq, const float* __restrict__ Wkv,
    const float* __restrict__ Wo, short* __restrict__ WT)
{
    const int t = threadIdx.x;
    if (blockIdx.x < 2048) {
        const int i = (blockIdx.x * 256 + t) * 8;
        float4 a = *(const float4*)(X + i);
        float4 b = *(const float4*)(X + i + 4);
        union { unsigned u[4]; s16x8 v; } o;
        o.u[0] = f2bf_pk(a.x, a.y); o.u[1] = f2bf_pk(a.z, a.w);
        o.u[2] = f2bf_pk(b.x, b.y); o.u[3] = f2bf_pk(b.z, b.w);
        *(s16x8*)(Y + i) = o.v;
    } else {
        const int i2 = blockIdx.x - 2048;
        const int bx = i2 & 63, by = i2 >> 6;
        const int ng = bx * 64 + (t & 63);           // 0..4095
        const int k0 = (by * 4 + (t >> 6)) * 8;
        const float* W; int n, N;
        if (ng < 1024)      { W = Wq;  n = ng;        N = 1024; }
        else if (ng < 3072) { W = Wkv; n = ng - 1024; N = 2048; }
        else                { W = Wo;  n = ng - 3072; N = 1024; }
        float v[8];
#pragma unroll
        for (int j = 0; j < 8; ++j) v[j] = W[(size_t)(k0 + j) * N + n];
        union { unsigned u[4]; s16x8 s; } o;
        o.u[0] = f2bf_pk(v[0], v[1]); o.u[1] = f2bf_pk(v[2], v[3]);
        o.u[2] = f2bf_pk(v[4], v[5]); o.u[3] = f2bf_pk(v[6], v[7]);
        *(s16x8*)&WT[(size_t)ng * 1024 + k0] = o.s;
    }
}

// ---------------- V part of QKV -> VtG[(b*NH+h)*64+dv][SEQ] ----------------
__global__ __launch_bounds__(256) void transpose_v_kernel(
    const short* __restrict__ QKV, short* __restrict__ VtG)
{
    const int t = threadIdx.x;
    const int tok0 = blockIdx.x * 64;
    const int h = blockIdx.y, b = blockIdx.z;
    __shared__ short L[64 * 72];
    const short* src = QKV + (size_t)(b * SEQ + tok0) * 3072 + 2048 + h * 64;
#pragma unroll
    for (int p = 0; p < 2; ++p) {
        int r = p * 32 + (t >> 3);
        *(s16x8*)&L[r * 72 + (t & 7) * 8] = *(const s16x8*)(src + (size_t)r * 3072 + (t & 7) * 8);
    }
    __syncthreads();
    short* dst = VtG + (size_t)(b * NHEADS + h) * 64 * SEQ + tok0;
#pragma unroll
    for (int p = 0; p < 2; ++p) {
        int u = p * 256 + t;
        int dv = u >> 3, c = (u & 7) * 8;
        s16x8 o;
#pragma unroll
        for (int j = 0; j < 8; ++j) o[j] = L[(c + j) * 72 + dv];
        *(s16x8*)(dst + (size_t)dv * SEQ + c) = o;
    }
}

// ---------------- bf16 MFMA GEMM: C = A @ Bt^T, epilogue (acc+bias)*scale ----------------
// r11: BK=32 restored (r9 form, best measured; r10's BK64+swizzle was -2.5us).
// QKV instantiation (TM=128) gets an XCD-region remap: 24x32 grid -> 8 rectangular
// regions of 8(m) x 12(n); per-XCD panel set = 8 A + 12 B panels = 5MB ~ L2 size,
// so panels are fetched ~once per XCD instead of streaming 26MB through 4MB L2.
template<int TM, bool OUT_BF16>
__global__ __launch_bounds__(256) void gemm_mfma_kernel(
    const short* __restrict__ A, const short* __restrict__ Bt,
    const float* __restrict__ bias0, const float* __restrict__ bias1, int nsplit,
    float s0, float s1, void* __restrict__ C, int M, int N)
{
    const int K = 1024;
    constexpr int NI = (TM == 128) ? 4 : 2;
    __shared__ short As[TM * 32];
    __shared__ short Bs[128 * 32];

    const int t    = threadIdx.x;
    const int wave = t >> 6;
    const int lane = t & 63;
    const int col  = lane & 15;
    const int quad = lane >> 4;

    int bx = blockIdx.x, by = blockIdx.y;
    if (TM == 128) {
        // XCD = linear%8 (HW round-robin). Region for XCD x: m-rows [(x&3)*8, +8),
        // n-cols [(x>>2)*12, +12). Bijective over the 24x32 grid (768 = 8*96).
        const int Lb = bx + 24 * by;
        const int x = Lb & 7, i = Lb >> 3;
        by = (x & 3) * 8 + (i & 7);
        bx = (x >> 2) * 12 + (i >> 3);
    }
    const int m0 = by * TM;
    const int n0 = bx * 128;
    const int wroff = (TM == 128) ? (wave >> 1) * 64 : 0;
    const int wcoff = (TM == 128) ? (wave & 1) * 64 : wave * 32;

    f32x4 acc[4][NI];
#pragma unroll
    for (int mi = 0; mi < 4; ++mi)
#pragma unroll
        for (int ni = 0; ni < NI; ++ni) acc[mi][ni] = (f32x4){0.f, 0.f, 0.f, 0.f};

    constexpr int RPW = TM / 4;
    const int ldrowA = wave * RPW + (lane >> 2);
    const int ldrowB = wave * 32  + (lane >> 2);
    const int ldcol  = (lane & 3) * 8;
    const short* Ag = A  + (size_t)(m0 + ldrowA) * K + ldcol;
    const short* Bg = Bt + (size_t)(n0 + ldrowB) * K + ldcol;
    short* AsW = &As[wave * RPW * 32];
    short* BsW = &Bs[wave * 1024];

    for (int k0 = 0; k0 < K; k0 += 32) {
        __syncthreads();
        gld16(Ag + k0, AsW);
        if (TM == 128) gld16(Ag + 16 * K + k0, AsW + 512);
        gld16(Bg + k0,          BsW);
        gld16(Bg + 16 * K + k0, BsW + 512);
        __syncthreads();

        s16x8 aA[4], bB[NI];
#pragma unroll
        for (int mi = 0; mi < 4; ++mi)
            aA[mi] = *(const s16x8*)&As[(wroff + 16 * mi + col) * 32 + quad * 8];
#pragma unroll
        for (int ni = 0; ni < NI; ++ni)
            bB[ni] = *(const s16x8*)&Bs[(wcoff + 16 * ni + col) * 32 + quad * 8];
#pragma unroll
        for (int mi = 0; mi < 4; ++mi)
#pragma unroll
            for (int ni = 0; ni < NI; ++ni)
                acc[mi][ni] = __builtin_amdgcn_mfma_f32_16x16x32_bf16(aA[mi], bB[ni], acc[mi][ni], 0, 0, 0);
    }

    float bias_v[NI], scale_v[NI];
#pragma unroll
    for (int ni = 0; ni < NI; ++ni) {
        int nb = n0 + wcoff + 16 * ni + col;
        bias_v[ni]  = (nb < nsplit) ? bias0[nb] : bias1[nb - nsplit];
        scale_v[ni] = (nb < nsplit) ? s0 : s1;
    }

#pragma unroll
    for (int mi = 0; mi < 4; ++mi)
#pragma unroll
        for (int ni = 0; ni < NI; ++ni)
#pragma unroll
            for (int r = 0; r < 4; ++r) {
                const int gm = m0 + wroff + 16 * mi + quad * 4 + r;
                const int gn = n0 + wcoff + 16 * ni + col;
                float v = (acc[mi][ni][r] + bias_v[ni]) * scale_v[ni];
                if (OUT_BF16) ((short*)C)[(size_t)gm * N + gn] = f2bf(v);
                else          ((float*)C)[(size_t)gm * N + gn] = v;
            }
}

// ---------------- MFMA flash attention v15 (UNCHANGED: 56.1-56.3us measured) ----------
// v7 structure: 128-q tile, 8 waves = 4 q-quarters x 2 key-halves, double-buffered K/Vt,
// ONE barrier/iter, P via per-wave LDS (x32 PV full-rate). + XCD remap (FETCH 69.7->12.3MB).
__global__ __launch_bounds__(512, 4) void attn_v15_kernel(
    const short* __restrict__ QKV,  // [B*S, 3072] bf16 (Q scaled)
    const short* __restrict__ VtG,  // [(b*NH+h)*64+dv][SEQ] bf16
    short* __restrict__ O)          // [B*S, 1024] bf16
{
    const int L = blockIdx.x + 16 * blockIdx.y + 256 * blockIdx.z;  // 0..511
    const int xcd = L & 7, idx = L >> 3;
    const int pair = xcd * 4 + (idx >> 4);     // (b,h) pair, grouped per XCD (2MB L2 set)
    const int qt = idx & 15;
    const int h  = pair & 15;
    const int b  = pair >> 4;
    const int t  = threadIdx.x;
    const int wave = t >> 6;
    const int lane = t & 63;
    const int col  = lane & 15;
    const int quad = lane >> 4;
    const int wq = wave & 3;        // q-quarter (32 rows)
    const int kh = wave >> 2;       // key half (32 of 64)

    // arena 57,344 B: Ks 2x[64*72] | Vt 2x[64*72] | Ps 8x[32*40]
    __shared__ __align__(16) short Lds[28672];
    short* KsB = Lds;                          // + cur*4608
    short* VtB = Lds + 2 * 64 * 72;            // + cur*4608
    short* PsW = Lds + 4 * 64 * 72 + wave * (32 * 40);

    const short* Qg = QKV + (size_t)(b * SEQ + qt * 128) * 3072 + h * DH;
    const short* Kg = QKV + (size_t)(b * SEQ) * 3072 + 1024 + h * DH;
    const short* VtRow = VtG + (size_t)(b * NHEADS + h) * 64 * SEQ;

    // Q B-frags straight from global
    s16x8 aQ[2][2];
#pragma unroll
    for (int tq = 0; tq < 2; ++tq)
#pragma unroll
        for (int kq = 0; kq < 2; ++kq)
            aQ[tq][kq] = *(const s16x8*)(Qg + (size_t)(wq * 32 + 16 * tq + col) * 3072 + kq * 32 + quad * 8);

    f32x4 oa[4][2];                 // [td][tq] : O^T[dv][q] partial (this key half)
    float lsum[2] = {0.f, 0.f};
#pragma unroll
    for (int td = 0; td < 4; ++td)
#pragma unroll
        for (int tq = 0; tq < 2; ++tq) oa[td][tq] = (f32x4){0.f, 0.f, 0.f, 0.f};

    // stagers: 512 threads; srow = token-row (K) / dv-row (Vt), chunk of 16 B
    const int srow = t >> 3;         // 0..63
    const int sc8  = (t & 7) * 8;
    const short* KgS  = Kg + (size_t)srow * 3072 + sc8;
    const short* VtgS = VtRow + (size_t)srow * SEQ + sc8;
    s16x8 kx = *(const s16x8*)KgS;
    s16x8 vx = *(const s16x8*)VtgS;

    for (int kt = 0; kt < SEQ / 64; ++kt) {
        const int cur = kt & 1;
        *(s16x8*)&KsB[cur * 4608 + srow * 72 + sc8] = kx;
        *(s16x8*)&VtB[cur * 4608 + srow * 72 + sc8] = vx;
        {   // prefetch next tile into regs (clamped)
            int nt = (kt + 1 < SEQ / 64) ? kt + 1 : kt;
            kx = *(const s16x8*)(KgS + (size_t)nt * 64 * 3072);
            vx = *(const s16x8*)(VtgS + (size_t)nt * 64);
        }
        __syncthreads();   // double-buffered: single barrier per iter

        // S^T[key(32 of this half)][q(32)] = K . Q^T   (pre-scaled)
        s16x8 aK[2][2];
#pragma unroll
        for (int tk = 0; tk < 2; ++tk)
#pragma unroll
            for (int kq = 0; kq < 2; ++kq)
                aK[tk][kq] = *(const s16x8*)&KsB[cur * 4608 + (kh * 32 + 16 * tk + col) * 72 + kq * 32 + quad * 8];
        f32x4 st[2][2];
        __builtin_amdgcn_s_setprio(1);
#pragma unroll
        for (int tk = 0; tk < 2; ++tk)
#pragma unroll
            for (int tq = 0; tq < 2; ++tq) {
                f32x4 a = (f32x4){0.f, 0.f, 0.f, 0.f};
                a = __builtin_amdgcn_mfma_f32_16x16x32_bf16(aK[tk][0], aQ[tq][0], a, 0, 0, 0);
                a = __builtin_amdgcn_mfma_f32_16x16x32_bf16(aK[tk][1], aQ[tq][1], a, 0, 0, 0);
                st[tk][tq] = a;
            }
        __builtin_amdgcn_s_setprio(0);

        // P = exp2(S^T); b64 writes into P[q][key_local]
#pragma unroll
        for (int tk = 0; tk < 2; ++tk)
#pragma unroll
            for (int tq = 0; tq < 2; ++tq) {
                float p0 = EXP2(st[tk][tq][0]);
                float p1 = EXP2(st[tk][tq][1]);
                float p2 = EXP2(st[tk][tq][2]);
                float p3 = EXP2(st[tk][tq][3]);
                lsum[tq] += (p0 + p1) + (p2 + p3);
                *(s16x4*)&PsW[(16 * tq + col) * 40 + 16 * tk + quad * 4] = pk4(p0, p1, p2, p3);
            }
        asm volatile("s_waitcnt lgkmcnt(0)" ::: "memory");   // P wave-private

        // O^T += V^T . P
        s16x8 bP[2];
#pragma unroll
        for (int tq = 0; tq < 2; ++tq)
            bP[tq] = *(const s16x8*)&PsW[(16 * tq + col) * 40 + quad * 8];
        __builtin_amdgcn_s_setprio(1);
#pragma unroll
        for (int td = 0; td < 4; ++td) {
            const int dv = 16 * td + col;
            s16x8 aV = *(const s16x8*)&VtB[cur * 4608 + dv * 72 + kh * 32 + quad * 8];
#pragma unroll
            for (int tq = 0; tq < 2; ++tq)
                oa[td][tq] = __builtin_amdgcn_mfma_f32_16x16x32_bf16(aV, bP[tq], oa[td][tq], 0, 0, 0);
        }
        __builtin_amdgcn_s_setprio(0);
    }

    // reduce lsum over quad halves (keys spread across quads)
#pragma unroll
    for (int tq = 0; tq < 2; ++tq) {
        lsum[tq] += __shfl_xor(lsum[tq], 16);
        lsum[tq] += __shfl_xor(lsum[tq], 32);
    }

    // cross-wave (key-half) fp32 merge via LDS: single round, 4 slots
    __syncthreads();
    float* red  = (float*)Lds;
    float* redl = red + 4 * 64 * 36;
    if (wave >= 4) {
        const int slot = wave & 3;
#pragma unroll
        for (int td = 0; td < 4; ++td)
#pragma unroll
            for (int tq = 0; tq < 2; ++tq)
#pragma unroll
                for (int r = 0; r < 4; ++r)
                    red[slot * 2304 + (16 * td + quad * 4 + r) * 36 + 16 * tq + col] = oa[td][tq][r];
        if (quad == 0)
#pragma unroll
            for (int tq = 0; tq < 2; ++tq)
                redl[slot * 32 + 16 * tq + col] = lsum[tq];
    }
    __syncthreads();

    // merge + normalize + write (waves 0..3 only)
    if (wave < 4) {
        const int slot = wq;
#pragma unroll
        for (int td = 0; td < 4; ++td)
#pragma unroll
            for (int tq = 0; tq < 2; ++tq)
#pragma unroll
                for (int r = 0; r < 4; ++r)
                    oa[td][tq][r] += red[slot * 2304 + (16 * td + quad * 4 + r) * 36 + 16 * tq + col];
        float inv[2];
#pragma unroll
        for (int tq = 0; tq < 2; ++tq) {
            lsum[tq] += redl[slot * 32 + 16 * tq + col];
            inv[tq] = 1.f / lsum[tq];
        }
        short* Og = O + (size_t)(b * SEQ + qt * 128 + wq * 32) * DIM + h * DH;
#pragma unroll
        for (int td = 0; td < 4; ++td)
#pragma unroll
            for (int tq = 0; tq < 2; ++tq)
                *(s16x4*)(Og + (size_t)(16 * tq + col) * DIM + 16 * td + quad * 4) =
                    pk4(oa[td][tq][0] * inv[tq], oa[td][tq][1] * inv[tq],
                        oa[td][tq][2] * inv[tq], oa[td][tq][3] * inv[tq]);
    }
}

extern "C" void kernel_launch(void* const* d_in, const int* in_sizes, int n_in,
                              void* d_out, int out_size, void* d_ws, size_t ws_size,
                              hipStream_t stream)
{
    const float* q   = (const float*)d_in[0];
    const float* Wq  = (const float*)d_in[1];
    const float* bq  = (const float*)d_in[2];
    const float* Wkv = (const float*)d_in[3];
    const float* bkv = (const float*)d_in[4];
    const float* Wo  = (const float*)d_in[5];
    const float* bo  = (const float*)d_in[6];
    float* out = (float*)d_out;

    const int M = BATCH * SEQ;   // 4096

    // ws (48 MB): qb 8 | WT_all 8 | QKV 24 | AO 8.  VtG (8 MB) lives in d_out (dead before out-GEMM).
    short* qb     = (short*)d_ws;
    short* WT     = qb     + (size_t)M * DIM;             // [4096][1024]: Wq|Wkv|Wo transposed
    short* QKVbuf = WT     + (size_t)4096 * DIM;
    short* AObuf  = QKVbuf + (size_t)M * 3 * DIM;
    short* VtG    = (short*)d_out;

    const float QSCALE = 0.18033688011112042f;   // 0.125 * log2(e)

    prep_kernel<<<4096, 256, 0, stream>>>(q, qb, Wq, Wkv, Wo, WT);

    gemm_mfma_kernel<128, true><<<dim3(3 * DIM / 128, M / 128), 256, 0, stream>>>(
        qb, WT, bq, bkv, DIM, QSCALE, 1.0f, QKVbuf, M, 3 * DIM);
    transpose_v_kernel<<<dim3(SEQ / 64, NHEADS, BATCH), 256, 0, stream>>>(QKVbuf, VtG);
    attn_v15_kernel<<<dim3(SEQ / 128, NHEADS, BATCH), 512, 0, stream>>>(QKVbuf, VtG, AObuf);
    gemm_mfma_kernel<64, false><<<dim3(DIM / 128, M / 64), 256, 0, stream>>>(
        AObuf, WT + (size_t)3072 * 1024, bo, bo, 1 << 30, 1.0f, 1.0f, out, M, DIM);
}